// Round 5
// baseline (405.827 us; speedup 1.0000x reference)
//
#include <hip/hip_runtime.h>
#include <math.h>

// Problem constants (from reference)
#define NM       16     // total SH components l=0..3
#define NQ       32     // N_PSEUDO * N_MAX
#define CUT      5.0f
#define CAP      96     // per-node edge capacity (max degree ~45 here)
#define FSTRIDE  48     // floats per edge feature record: Y[16] + W[32]

typedef float v4f __attribute__((ext_vector_type(4)));

// ---------------------------------------------------------------------------
// Kernel 1: per-edge geometry + features at FULL 64-lane efficiency.
// For each passing edge (r < CUT): bin its id by destination node, and write
// a 48-float record {Y[16], W[32]} where W[p*8+n] = semb[sj][p] * R[n] * fcut.
// ---------------------------------------------------------------------------
__global__ __launch_bounds__(256) void edge_feat_kernel(
    const float* __restrict__ pos,      // [N][3]
    const float* __restrict__ cells,    // [1][3][3]
    const int*   __restrict__ species,  // [N]
    const int*   __restrict__ eidx,     // [2][E]
    const int*   __restrict__ eshift,   // [E][3]
    const float* __restrict__ semb,     // [4][4]
    const float* __restrict__ mu,       // [8]
    const float* __restrict__ sigma,    // [1]
    int*         __restrict__ counts,   // [N]
    int*         __restrict__ ids,      // [N][CAP]
    float*       __restrict__ feat,     // [E][FSTRIDE]
    int E)
{
    const int e = blockIdx.x * blockDim.x + threadIdx.x;
    if (e >= E) return;

    const int i = eidx[e];
    const int j = eidx[E + e];

    float dx = pos[3 * j + 0] - pos[3 * i + 0];
    float dy = pos[3 * j + 1] - pos[3 * i + 1];
    float dz = pos[3 * j + 2] - pos[3 * i + 2];

    const int sx = eshift[3 * e + 0];
    const int sy = eshift[3 * e + 1];
    const int sz = eshift[3 * e + 2];
    dx += (float)sx * cells[0] + (float)sy * cells[3] + (float)sz * cells[6];
    dy += (float)sx * cells[1] + (float)sy * cells[4] + (float)sz * cells[7];
    dz += (float)sx * cells[2] + (float)sy * cells[5] + (float)sz * cells[8];

    const float r2 = dx * dx + dy * dy + dz * dz;
    if (r2 >= CUT * CUT) return;        // fcut == 0 -> exact zero contribution

    const int slot = atomicAdd(&counts[i], 1);
    if (slot >= CAP) return;
    ids[(size_t)i * CAP + slot] = e;

    const float r    = sqrtf(r2 + 1e-12f);
    const float invr = 1.0f / r;
    const float x = dx * invr, y = dy * invr, z = dz * invr;
    const float x2 = x * x, y2 = y * y, z2 = z * z;

    v4f* fp = (v4f*)(feat + (size_t)e * FSTRIDE);

    v4f Ya, Yb, Yc, Yd;
    Ya[0] = 0.28209479177387814f;
    Ya[1] = 0.4886025119029199f * y;
    Ya[2] = 0.4886025119029199f * z;
    Ya[3] = 0.4886025119029199f * x;
    Yb[0] = 1.0925484305920792f * x * y;
    Yb[1] = 1.0925484305920792f * y * z;
    Yb[2] = 0.31539156525252005f * (3.0f * z2 - 1.0f);
    Yb[3] = 1.0925484305920792f * x * z;
    Yc[0] = 0.5462742152960396f * (x2 - y2);
    Yc[1] = 0.5900435899266435f * y * (3.0f * x2 - y2);
    Yc[2] = 2.890611442640554f  * x * y * z;
    Yc[3] = 0.4570457994644658f * y * (5.0f * z2 - 1.0f);
    Yd[0] = 0.3731763325901154f * z * (5.0f * z2 - 3.0f);
    Yd[1] = 0.4570457994644658f * x * (5.0f * z2 - 1.0f);
    Yd[2] = 1.445305721320277f  * z * (x2 - y2);
    Yd[3] = 0.5900435899266435f * x * (x2 - 3.0f * y2);
    fp[0] = Ya; fp[1] = Yb; fp[2] = Yc; fp[3] = Yd;

    const float sig    = sigma[0];
    const float inv2s2 = -1.0f / (2.0f * sig * sig);
    const float fcut   = 0.5f * (__cosf(0.62831853071795864f * r) + 1.0f);

    float Rf[8];
#pragma unroll
    for (int n = 0; n < 8; ++n) {
        const float dr = r - mu[n];
        Rf[n] = __expf(dr * dr * inv2s2) * fcut;
    }
    const int sj = species[j];
#pragma unroll
    for (int p = 0; p < 4; ++p) {
        const float ejp = semb[sj * 4 + p];
        v4f w0, w1;
#pragma unroll
        for (int n = 0; n < 4; ++n) { w0[n] = ejp * Rf[n]; w1[n] = ejp * Rf[4 + n]; }
        fp[4 + 2 * p]     = w0;
        fp[4 + 2 * p + 1] = w1;
    }
}

// ---------------------------------------------------------------------------
// Kernel 2: wave-per-node accumulate + power spectrum. Per edge: one
// coalesced 128B read (W[q] per lane), two broadcast 16B reads (Y), 8 FMAs.
// No transcendentals, no staging LDS. c published to per-wave LDS only for
// the cross-lane PS phase; contiguous nontemporal float4 stores.
// ---------------------------------------------------------------------------
__global__ __launch_bounds__(256) void node_ps_kernel(
    const float* __restrict__ feat,   // [E][FSTRIDE]
    const int*   __restrict__ ids,    // [N][CAP]
    const int*   __restrict__ counts, // [N]
    float*       __restrict__ out,    // [N][4096]
    int N)
{
    const int wid  = threadIdx.x >> 6;
    const int lane = threadIdx.x & 63;
    const int node = blockIdx.x * 4 + wid;

    __shared__ __align__(16) float sc[4][NM * NQ];
    float* wc = sc[wid];

    if (node >= N) return;

    const int cnt = min(counts[node], CAP);
    const int q = lane & 31;        // owned c column
    const int h = lane >> 5;        // owned rows h*8 .. h*8+7
    const int* myids = ids + (size_t)node * CAP;

    v4f acc0 = {0.f, 0.f, 0.f, 0.f};
    v4f acc1 = {0.f, 0.f, 0.f, 0.f};

    int k = 0;
    for (; k + 2 <= cnt; k += 2) {
        const int e0 = myids[k];
        const int e1 = myids[k + 1];
        const float* f0 = feat + (size_t)e0 * FSTRIDE;
        const float* f1 = feat + (size_t)e1 * FSTRIDE;
        const float w0 = f0[16 + q];
        const float w1 = f1[16 + q];
        const v4f y00 = *(const v4f*)(f0 + h * 8);
        const v4f y01 = *(const v4f*)(f0 + h * 8 + 4);
        const v4f y10 = *(const v4f*)(f1 + h * 8);
        const v4f y11 = *(const v4f*)(f1 + h * 8 + 4);
        acc0 += y00 * w0; acc1 += y01 * w0;
        acc0 += y10 * w1; acc1 += y11 * w1;
    }
    if (k < cnt) {
        const int e0 = myids[k];
        const float* f0 = feat + (size_t)e0 * FSTRIDE;
        const float w0 = f0[16 + q];
        const v4f y00 = *(const v4f*)(f0 + h * 8);
        const v4f y01 = *(const v4f*)(f0 + h * 8 + 4);
        acc0 += y00 * w0; acc1 += y01 * w0;
    }

    // publish c[16][32] into the per-wave LDS region (intra-wave ordering)
#pragma unroll
    for (int jj = 0; jj < 4; ++jj) {
        wc[(h * 8 + jj) * NQ + q]     = acc0[jj];
        wc[(h * 8 + 4 + jj) * NQ + q] = acc1[jj];
    }

    // power spectrum: out4[node*1024 + l*256 + k*64 + lane]
    const float cg[4] = {1.0f, 0.57735026918962576f,
                         0.44721359549995794f, 0.37796447300922723f};
    const v4f* wc4 = (const v4f*)wc;
    const int  r4  = lane & 7;
    const int  qh  = lane >> 3;
    v4f* op = (v4f*)out + (size_t)node * 1024;

#pragma unroll
    for (int l = 0; l < 4; ++l) {
        const int mb = l * l;
        const int mc = 2 * l + 1;
        v4f bv[7];
#pragma unroll
        for (int m = 0; m < 7; ++m)
            if (m < mc) bv[m] = wc4[(mb + m) * 8 + r4];
        const float cgl = cg[l];
#pragma unroll
        for (int kk = 0; kk < 4; ++kk) {
            const int q2 = kk * 8 + qh;
            v4f s = {0.f, 0.f, 0.f, 0.f};
#pragma unroll
            for (int m = 0; m < 7; ++m)
                if (m < mc) s += wc[(mb + m) * NQ + q2] * bv[m];
            s *= cgl;
            __builtin_nontemporal_store(s, &op[l * 256 + kk * 64 + lane]);
        }
    }
}

// ---------------------------------------------------------------------------
extern "C" void kernel_launch(void* const* d_in, const int* in_sizes, int n_in,
                              void* d_out, int out_size, void* d_ws, size_t ws_size,
                              hipStream_t stream) {
    const float* pos     = (const float*)d_in[0];
    const float* cells   = (const float*)d_in[1];
    const int*   species = (const int*)  d_in[2];
    const int*   eidx    = (const int*)  d_in[3];
    const int*   eshift  = (const int*)  d_in[4];
    const float* semb    = (const float*)d_in[5];
    const float* mu      = (const float*)d_in[6];
    const float* sigma   = (const float*)d_in[7];
    float*       out     = (float*)d_out;

    const int N = in_sizes[0] / 3;
    const int E = in_sizes[3] / 2;

    // workspace layout
    float* feat = (float*)d_ws;                               // [E][48] floats
    size_t off  = (size_t)E * FSTRIDE * sizeof(float);
    int* ids    = (int*)((char*)d_ws + off);                  // [N][CAP]
    off += (size_t)N * CAP * sizeof(int);
    int* counts = (int*)((char*)d_ws + off);                  // [N]

    hipMemsetAsync(counts, 0, (size_t)N * sizeof(int), stream);

    edge_feat_kernel<<<(E + 255) / 256, 256, 0, stream>>>(
        pos, cells, species, eidx, eshift, semb, mu, sigma,
        counts, ids, feat, E);

    node_ps_kernel<<<(N + 3) / 4, 256, 0, stream>>>(
        feat, ids, counts, out, N);
}